// Round 13
// baseline (601.791 us; speedup 1.0000x reference)
//
#include <hip/hip_runtime.h>
#include <math.h>

#define B_ 4
#define CIN_ 32
#define HID_ 32
#define T_ 31
#define H_ 96
#define W_ 96
#define SP_ (H_*W_)
#define TSP (T_ * SP_)

typedef _Float16 half8 __attribute__((ext_vector_type(8)));
typedef float f32x4 __attribute__((ext_vector_type(4)));
typedef float f32x16 __attribute__((ext_vector_type(16)));

static __device__ inline unsigned int packhh(float a, float b) {
  unsigned short ua = __builtin_bit_cast(unsigned short, (_Float16)a);
  unsigned short ub = __builtin_bit_cast(unsigned short, (_Float16)b);
  return (unsigned int)ua | ((unsigned int)ub << 16);
}

// ---------------------------------------------------------------------------
// Kernel 0: weights fp32 -> fp16 gate-interleaved MFMA A-fragments.
// wr[((ocg*27 + tap)*64 + lane)*8 + i]
//   m = lane&15: gate = m&1, ch = ocg*8 + (m>>1); oc = gate*32 + ch
//   cin = (lane>>4)*8 + i
// ---------------------------------------------------------------------------
__global__ __launch_bounds__(256) void prep_w_kernel(
    const float* __restrict__ w, _Float16* __restrict__ wr) {
  int idx = blockIdx.x * 256 + threadIdx.x;
  if (idx >= 55296) return;
  int i = idx & 7;
  int lane = (idx >> 3) & 63;
  int rest = idx >> 9;             // ocg*27 + tap
  int tap = rest % 27;
  int ocg = rest / 27;
  int m = lane & 15;
  int cin = (lane >> 4) * 8 + i;
  int oc = (m & 1) * 32 + ocg * 8 + (m >> 1);
  wr[idx] = (_Float16)(w[(oc * CIN_ + cin) * 27 + tap]);
}

// ---------------------------------------------------------------------------
// Kernel 1: fused Conv3d (fp16 MFMA) + gating + SERIAL recurrence,
// PAIR-compute: (t, t+1) per barrier -> 16 phases instead of 31.
// R10/R11 proven frame (4 waves x 16 oc-slots, tile 16x6, grid 96x4,
// in-VGPR weights, packed fp16x2 h output, stores after barrier) with R9's
// pair inner loop (brow shared by acc0/acc1; 96 ds_read_b128 per wave-pair
// vs 144) minus R9's chunking (single prologue, FETCH stays ~290 MB).
// Ring: 6 slots x [8 rows x 18 cols][pitch 40] = 69 KB -> 2 blocks/CU.
// Pair t reads SLOT(t-1..t+2); stages t+3 -> SLOT(t-3), t+4 -> SLOT(t-2):
// disjoint; barrier at pair end orders writes before next pair reads.
// ---------------------------------------------------------------------------
#define PITCH 40
#define SROWS 8
#define SCOLS 18
#define RST (SCOLS * PITCH)
#define SLICE_HF (SROWS * RST)             // 5760 f16 = 11520 B
#define SLOT(s) ((((s) % 6) + 6) % 6)

__global__ __launch_bounds__(256, 2) void conv_rec_mfma(
    const float* __restrict__ in, const _Float16* __restrict__ wr,
    const float* __restrict__ bias, unsigned int* __restrict__ gout) {
  __shared__ _Float16 in_s[6 * SLICE_HF];   // 69120 B

  const int tid = threadIdx.x;
  const int tile = blockIdx.x;   // 0..95
  const int b = blockIdx.y;      // 0..3
  const int x0 = (tile % 6) * 16;
  const int y0 = (tile / 6) * 6;
  const int lane = tid & 63;
  const int ocg = tid >> 6;      // 0..3
  const int px = lane & 15;
  const int kq = lane >> 4;      // 0..3

  // per-wave weights: 27 taps, gate-interleaved 16-slot frags (108 VGPR)
  half8 wreg[27];
  {
    const _Float16* wp = wr + (size_t)ocg * 27 * 512 + lane * 8;
#pragma unroll
    for (int tap = 0; tap < 27; ++tap)
      wreg[tap] = *(const half8*)(wp + tap * 512);
  }

  const int c0 = ocg * 8 + 2 * kq;
  f32x4 bias4;
  bias4[0] = bias[c0];
  bias4[1] = bias[32 + c0];
  bias4[2] = bias[c0 + 1];
  bias4[3] = bias[32 + c0 + 1];

  // staging roles: interior 16 jobs x 16 px; edges 8 rows x 32 cin
  const int s_xi = tid & 15;
  const int s_q  = tid >> 4;
  const int e_cin = tid & 31;
  const int e_yy  = tid >> 5;
  const int e_gy  = y0 - 1 + e_yy;
  const bool e_ok = ((unsigned)e_gy < (unsigned)H_);
  const bool has_l = (x0 > 0), has_r = (x0 + 16 < W_);

  const float* inb = in + (size_t)(b * CIN_) * TSP;

  auto zero_slot = [&](int slot) {
    uint32_t* dz = (uint32_t*)(in_s + slot * SLICE_HF);
    for (int e = tid; e < SLICE_HF / 2; e += 256) dz[e] = 0u;
  };
  auto stage_full = [&](int ts) {   // prologue only
    _Float16* dst = in_s + SLOT(ts) * SLICE_HF;
    const int tso = ts * SP_;
#pragma unroll
    for (int k = 0; k < 16; ++k) {
      int rj = k * 16 + s_q;
      int cin = rj & 31;
      int yy = rj >> 5;
      int gy = y0 - 1 + yy;
      float v = 0.f;
      if ((unsigned)gy < (unsigned)H_)
        v = inb[(size_t)cin * TSP + tso + gy * W_ + x0 + s_xi];
      dst[(yy * SCOLS + s_xi + 1) * PITCH + cin] = (_Float16)v;
    }
    float v0 = 0.f, v1 = 0.f;
    if (e_ok) {
      const float* rb = inb + (size_t)e_cin * TSP + tso + e_gy * W_;
      if (has_l) v0 = rb[x0 - 1];
      if (has_r) v1 = rb[x0 + 16];
    }
    dst[(e_yy * SCOLS + 0) * PITCH + e_cin] = (_Float16)v0;
    dst[(e_yy * SCOLS + 17) * PITCH + e_cin] = (_Float16)v1;
  };

  // prologue: SLOT(-1)=SLOT(5) zeros; slices 0,1,2 staged
  zero_slot(5);
  stage_full(0);
  stage_full(1);
  stage_full(2);
  __syncthreads();

  float h[6][2];
#pragma unroll
  for (int r = 0; r < 6; ++r) { h[r][0] = 0.f; h[r][1] = 0.f; }

  const int pr = ocg * 4 + kq;   // packed pair plane 0..15
  size_t obase = ((size_t)(b * 32 + pr) * T_) * SP_ + y0 * W_ + x0 + px;

  // brow column offsets (no swizzle; unswizzled 8-lane groups conflict-free)
  int cs[3];
#pragma unroll
  for (int kw = 0; kw < 3; ++kw) cs[kw] = (px + kw) * PITCH + kq * 8;

  for (int t0 = 0; t0 < T_; t0 += 2) {
    const bool hasT1 = (t0 + 1 < T_);
    const int ts0 = t0 + 3, ts1 = t0 + 4;
    const bool stA = (ts0 < T_);
    const bool zA  = (ts0 == T_);
    const bool stB = (ts1 < T_);

    // ---- issue stage loads A (slice ts0) ----
    float svA[16], evA0 = 0.f, evA1 = 0.f;
    if (stA) {
      const int tso = ts0 * SP_;
#pragma unroll
      for (int kk = 0; kk < 16; ++kk) {
        int rj = kk * 16 + s_q;
        int cin = rj & 31;
        int yy = rj >> 5;
        int gy = y0 - 1 + yy;
        svA[kk] = 0.f;
        if ((unsigned)gy < (unsigned)H_)
          svA[kk] = inb[(size_t)cin * TSP + tso + gy * W_ + x0 + s_xi];
      }
      if (e_ok) {
        const float* rb = inb + (size_t)e_cin * TSP + tso + e_gy * W_;
        if (has_l) evA0 = rb[x0 - 1];
        if (has_r) evA1 = rb[x0 + 16];
      }
    }

    f32x4 acc0[6], acc1[6];
#pragma unroll
    for (int r = 0; r < 6; ++r) { acc0[r] = bias4; acc1[r] = bias4; }

    // ---- slices s=0,1 (t0-1, t0): acc0 kd=s; acc1 kd=0 at s==1 ----
#pragma unroll
    for (int s = 0; s < 2; ++s) {
      const _Float16* sb2 = in_s + SLOT(t0 - 1 + s) * SLICE_HF;
#pragma unroll
      for (int kw = 0; kw < 3; ++kw) {
        half8 brow[8];
#pragma unroll
        for (int rr = 0; rr < 8; ++rr)
          brow[rr] = *(const half8*)(sb2 + rr * RST + cs[kw]);
#pragma unroll
        for (int kh = 0; kh < 3; ++kh) {
          const int tap0 = s * 9 + kh * 3 + kw;
#pragma unroll
          for (int r = 0; r < 6; ++r)
            acc0[r] = __builtin_amdgcn_mfma_f32_16x16x32_f16(wreg[tap0], brow[r + kh], acc0[r], 0, 0, 0);
          if (s == 1) {
            const int tap1 = kh * 3 + kw;
#pragma unroll
            for (int r = 0; r < 6; ++r)
              acc1[r] = __builtin_amdgcn_mfma_f32_16x16x32_f16(wreg[tap1], brow[r + kh], acc1[r], 0, 0, 0);
          }
        }
      }
    }

    // ---- write A -> SLOT(ts0) = SLOT(t0-3), outside read window ----
    if (stA) {
      _Float16* dst = in_s + SLOT(ts0) * SLICE_HF;
#pragma unroll
      for (int kk = 0; kk < 16; ++kk) {
        int rj = kk * 16 + s_q;
        int cin = rj & 31;
        int yy = rj >> 5;
        dst[(yy * SCOLS + s_xi + 1) * PITCH + cin] = (_Float16)svA[kk];
      }
      dst[(e_yy * SCOLS + 0) * PITCH + e_cin] = (_Float16)evA0;
      dst[(e_yy * SCOLS + 17) * PITCH + e_cin] = (_Float16)evA1;
    } else if (zA) {
      zero_slot(SLOT(ts0));
    }

    // ---- issue stage loads B (slice ts1) ----
    float svB[16], evB0 = 0.f, evB1 = 0.f;
    if (stB) {
      const int tso = ts1 * SP_;
#pragma unroll
      for (int kk = 0; kk < 16; ++kk) {
        int rj = kk * 16 + s_q;
        int cin = rj & 31;
        int yy = rj >> 5;
        int gy = y0 - 1 + yy;
        svB[kk] = 0.f;
        if ((unsigned)gy < (unsigned)H_)
          svB[kk] = inb[(size_t)cin * TSP + tso + gy * W_ + x0 + s_xi];
      }
      if (e_ok) {
        const float* rb = inb + (size_t)e_cin * TSP + tso + e_gy * W_;
        if (has_l) evB0 = rb[x0 - 1];
        if (has_r) evB1 = rb[x0 + 16];
      }
    }

    // ---- slices s=2,3: acc0 kd=2 at s==2; acc1 kd=s-1 ----
    // (t0==30: s=2 slice 31 is zeroed; s=3 slice 32 stale -> acc1 discarded)
#pragma unroll
    for (int s = 2; s < 4; ++s) {
      const _Float16* sb2 = in_s + SLOT(t0 - 1 + s) * SLICE_HF;
#pragma unroll
      for (int kw = 0; kw < 3; ++kw) {
        half8 brow[8];
#pragma unroll
        for (int rr = 0; rr < 8; ++rr)
          brow[rr] = *(const half8*)(sb2 + rr * RST + cs[kw]);
#pragma unroll
        for (int kh = 0; kh < 3; ++kh) {
          if (s == 2) {
            const int tap0 = 18 + kh * 3 + kw;
#pragma unroll
            for (int r = 0; r < 6; ++r)
              acc0[r] = __builtin_amdgcn_mfma_f32_16x16x32_f16(wreg[tap0], brow[r + kh], acc0[r], 0, 0, 0);
          }
          const int tap1 = (s - 1) * 9 + kh * 3 + kw;
#pragma unroll
          for (int r = 0; r < 6; ++r)
            acc1[r] = __builtin_amdgcn_mfma_f32_16x16x32_f16(wreg[tap1], brow[r + kh], acc1[r], 0, 0, 0);
        }
      }
    }

    // ---- write B -> SLOT(ts1) = SLOT(t0-2), outside read window ----
    if (stB) {
      _Float16* dst = in_s + SLOT(ts1) * SLICE_HF;
#pragma unroll
      for (int kk = 0; kk < 16; ++kk) {
        int rj = kk * 16 + s_q;
        int cin = rj & 31;
        int yy = rj >> 5;
        dst[(yy * SCOLS + s_xi + 1) * PITCH + cin] = (_Float16)svB[kk];
      }
      dst[(e_yy * SCOLS + 0) * PITCH + e_cin] = (_Float16)evB0;
      dst[(e_yy * SCOLS + 17) * PITCH + e_cin] = (_Float16)evB1;
    }

    // ---- gating + recurrence for t0 then t0+1 (order matters) ----
    unsigned int pk0[6], pk1[6];
#pragma unroll
    for (int r = 0; r < 6; ++r) {
      float z0 = 1.f - 2.f / (1.f + __expf(2.f * acc0[r][0]));
      float f0 = 1.f / (1.f + __expf(-acc0[r][1]));
      h[r][0] = f0 * h[r][0] + (1.f - f0) * z0;
      float z1 = 1.f - 2.f / (1.f + __expf(2.f * acc0[r][2]));
      float f1 = 1.f / (1.f + __expf(-acc0[r][3]));
      h[r][1] = f1 * h[r][1] + (1.f - f1) * z1;
      pk0[r] = packhh(h[r][0], h[r][1]);
    }
    if (hasT1) {
#pragma unroll
      for (int r = 0; r < 6; ++r) {
        float z0 = 1.f - 2.f / (1.f + __expf(2.f * acc1[r][0]));
        float f0 = 1.f / (1.f + __expf(-acc1[r][1]));
        h[r][0] = f0 * h[r][0] + (1.f - f0) * z0;
        float z1 = 1.f - 2.f / (1.f + __expf(2.f * acc1[r][2]));
        float f1 = 1.f / (1.f + __expf(-acc1[r][3]));
        h[r][1] = f1 * h[r][1] + (1.f - f1) * z1;
        pk1[r] = packhh(h[r][0], h[r][1]);
      }
    }
    __syncthreads();   // staged slices visible; ring safety for next pair

    // ---- stores after barrier (drain covered by next barrier) ----
#pragma unroll
    for (int r = 0; r < 6; ++r) gout[obase + r * W_] = pk0[r];
    if (hasT1) {
#pragma unroll
      for (int r = 0; r < 6; ++r) gout[obase + SP_ + r * W_] = pk1[r];
    }
    obase += 2 * SP_;
  }
}

// ---------------------------------------------------------------------------
// Kernel 2: per-pixel channel attention via 32x32x16 MFMA. (proven)
// Reads packed f16x2 h from u32-planes b*32+pr at own (y,x) tile; writes
// final f32 to planes b*32+c at the same tile -> no cross-block aliasing.
// ---------------------------------------------------------------------------
#define APIT 40
#define PSTR 1288

__global__ __launch_bounds__(512) void attn_mfma(
    unsigned int* __restrict__ g, const float* __restrict__ gamma) {
  __shared__ _Float16 qh_s[16 * PSTR];      // 41216 B
  __shared__ _Float16 qt_s[16 * PSTR];      // 41216 B
  __shared__ _Float16 at_s[8 * 32 * APIT];  // 20480 B

  const int tid = threadIdx.x;
  const int x0 = blockIdx.x * 16;
  const int y = blockIdx.y;
  const int b = blockIdx.z;
  const int lane = tid & 63;
  const int wv = tid >> 6;       // 0..7
  const float gm = gamma[0];

  for (int e = tid; e < 16 * 16 * 31; e += 512) {
    int xi = e & 15;
    int q = e >> 4;
    int t = q % 31;
    int pr = q / 31;
    unsigned int gw = g[((size_t)(b * 32 + pr) * T_ + t) * SP_ + y * W_ + x0 + xi];
    _Float16 h0 = __builtin_bit_cast(_Float16, (unsigned short)(gw & 0xffff));
    _Float16 h1 = __builtin_bit_cast(_Float16, (unsigned short)(gw >> 16));
    int c0 = 2 * pr;
    qh_s[xi * PSTR + c0 * APIT + t] = h0;
    qh_s[xi * PSTR + (c0 + 1) * APIT + t] = h1;
    qt_s[xi * PSTR + t * APIT + c0] = h0;
    qt_s[xi * PSTR + t * APIT + c0 + 1] = h1;
  }
  qh_s[(tid & 15) * PSTR + (tid >> 4) * APIT + 31] = (_Float16)0.f;
  __syncthreads();

  const int cd = lane & 31;
  const int hi = lane >> 5;

#pragma unroll
  for (int pp = 0; pp < 2; ++pp) {
    const int px = wv * 2 + pp;
    const _Float16* qs = qh_s + px * PSTR;
    const _Float16* qt = qt_s + px * PSTR;
    _Float16* as = at_s + wv * (32 * APIT);

    half8 q0 = *(const half8*)(qs + cd * APIT + hi * 8);
    half8 q1 = *(const half8*)(qs + cd * APIT + hi * 8 + 16);
    f32x16 S = {};
    S = __builtin_amdgcn_mfma_f32_32x32x16_f16(q0, q0, S, 0, 0, 0);
    S = __builtin_amdgcn_mfma_f32_32x32x16_f16(q1, q1, S, 0, 0, 0);

    float mx = S[0];
#pragma unroll
    for (int r = 1; r < 16; ++r) mx = fmaxf(mx, S[r]);
    mx = fmaxf(mx, __shfl_xor(mx, 32));
    float sm = 0.f;
    float ev[16];
#pragma unroll
    for (int r = 0; r < 16; ++r) { ev[r] = __expf(S[r] - mx); sm += ev[r]; }
    sm += __shfl_xor(sm, 32);
    const float sc = 0.17677669529663688f / sm;

#pragma unroll
    for (int r = 0; r < 16; ++r) {
      int c = (r & 3) + 8 * (r >> 2) + 4 * hi;
      as[c * APIT + cd] = (_Float16)(ev[r] * sc);
    }

    half8 a0 = *(const half8*)(as + cd * APIT + hi * 8);
    half8 a1 = *(const half8*)(as + cd * APIT + hi * 8 + 16);
    half8 b0 = *(const half8*)(qt + cd * APIT + hi * 8);
    half8 b1 = *(const half8*)(qt + cd * APIT + hi * 8 + 16);
    f32x16 P = {};
    P = __builtin_amdgcn_mfma_f32_32x32x16_f16(a0, b0, P, 0, 0, 0);
    P = __builtin_amdgcn_mfma_f32_32x32x16_f16(a1, b1, P, 0, 0, 0);

#pragma unroll
    for (int r = 0; r < 16; ++r) {
      int c = (r & 3) + 8 * (r >> 2) + 4 * hi;
      qt_s[px * PSTR + cd * APIT + c] = (_Float16)P[r];
    }
  }
  __syncthreads();

  float* gf = (float*)g;
  for (int e = tid; e < 4 * 992; e += 512) {
    int xi4 = e & 3;
    int q = e >> 2;
    int t = q % 31;
    int c = q / 31;
    float4 rv;
#pragma unroll
    for (int j = 0; j < 4; ++j) {
      int xi = xi4 * 4 + j;
      float ah = (float)qt_s[xi * PSTR + t * APIT + c];
      float hv = (float)qh_s[xi * PSTR + c * APIT + t];
      (&rv.x)[j] = gm * ah + hv;
    }
    *(float4*)&gf[((size_t)(b * HID_ + c) * T_ + t) * SP_ + y * W_ + x0 +
                  xi4 * 4] = rv;
  }
}

// ---------------------------------------------------------------------------
extern "C" void kernel_launch(void* const* d_in, const int* in_sizes, int n_in,
                              void* d_out, int out_size, void* d_ws,
                              size_t ws_size, hipStream_t stream) {
  const float* in    = (const float*)d_in[0];  // [4,32,31,96,96]
  const float* w     = (const float*)d_in[1];  // [64,32,3,3,3]
  const float* bias  = (const float*)d_in[2];  // [64]
  const float* gamma = (const float*)d_in[3];  // [1]
  _Float16* wr = (_Float16*)d_ws;              // 110 KB fp16 fragments

  prep_w_kernel<<<216, 256, 0, stream>>>(w, wr);
  conv_rec_mfma<<<dim3(96, 4), 256, 0, stream>>>(
      in, wr, bias, (unsigned int*)d_out);
  attn_mfma<<<dim3(6, 96, 4), 512, 0, stream>>>(
      (unsigned int*)d_out, gamma);
}

// Round 14
// 405.002 us; speedup vs baseline: 1.4859x; 1.4859x over previous
//
#include <hip/hip_runtime.h>
#include <math.h>

#define B_ 4
#define CIN_ 32
#define HID_ 32
#define T_ 31
#define H_ 96
#define W_ 96
#define SP_ (H_*W_)
#define TSP (T_ * SP_)

typedef _Float16 half8 __attribute__((ext_vector_type(8)));
typedef float f32x4 __attribute__((ext_vector_type(4)));
typedef float f32x16 __attribute__((ext_vector_type(16)));

static __device__ inline unsigned int packhh(float a, float b) {
  unsigned short ua = __builtin_bit_cast(unsigned short, (_Float16)a);
  unsigned short ub = __builtin_bit_cast(unsigned short, (_Float16)b);
  return (unsigned int)ua | ((unsigned int)ub << 16);
}

// ---------------------------------------------------------------------------
// Kernel 0: weights fp32 -> fp16 gate-interleaved MFMA A-fragments.
// wr[((ocg*27 + tap)*64 + lane)*8 + i]
//   m = lane&15: gate = m&1, ch = ocg*8 + (m>>1); oc = gate*32 + ch
//   cin = (lane>>4)*8 + i
// ---------------------------------------------------------------------------
__global__ __launch_bounds__(256) void prep_w_kernel(
    const float* __restrict__ w, _Float16* __restrict__ wr) {
  int idx = blockIdx.x * 256 + threadIdx.x;
  if (idx >= 55296) return;
  int i = idx & 7;
  int lane = (idx >> 3) & 63;
  int rest = idx >> 9;             // ocg*27 + tap
  int tap = rest % 27;
  int ocg = rest / 27;
  int m = lane & 15;
  int cin = (lane >> 4) * 8 + i;
  int oc = (m & 1) * 32 + ocg * 8 + (m >> 1);
  wr[idx] = (_Float16)(w[(oc * CIN_ + cin) * 27 + tap]);
}

// ---------------------------------------------------------------------------
// Kernel 1: fused Conv3d (fp16 MFMA) + gating + serial recurrence,
// WAVE-PARALLEL PAIR: 512 thr = 2 groups x 4 waves. Group A convs even t,
// group B odd t (convs independent); recurrence state h lives in LDS hx
// (6 KB packed fp16x2): A gates t0 (RMW hx) -> bar-mid -> B gates t1 (RMW
// hx) -> bar-end. 16 phases instead of 31. Each group has exactly R10's
// register budget (one acc set, one sv set) -> no spill (R13's failure).
// Ring: 6 slots x [8 rows x 18 cols][pitch 40] + hx = 75.3 KB -> 2 blk/CU.
// Slot safety per phase (t0): reads SLOT(t0-1..t0+2); A writes
// SLOT(t0+3)=SLOT(t0-3), B writes SLOT(t0+4)=SLOT(t0-2) - disjoint.
// launch_bounds(512,4) pins VGPR<=128 (R10's proven allocation).
// Stores after bar-end (R11). h packed fp16x2 out, as R10.
// ---------------------------------------------------------------------------
#define PITCH 40
#define SROWS 8
#define SCOLS 18
#define RST (SCOLS * PITCH)
#define SLICE_HF (SROWS * RST)             // 5760 f16 = 11520 B
#define SLOT(s) ((((s) % 6) + 6) % 6)

__global__ __launch_bounds__(512, 4) void conv_rec_mfma(
    const float* __restrict__ in, const _Float16* __restrict__ wr,
    const float* __restrict__ bias, unsigned int* __restrict__ gout) {
  __shared__ _Float16 in_s[6 * SLICE_HF];   // 69120 B
  __shared__ unsigned int hx_s[16 * 96];    // 6144 B packed h state

  const int tid = threadIdx.x;
  const int tile = blockIdx.x;   // 0..95
  const int b = blockIdx.y;      // 0..3
  const int x0 = (tile % 6) * 16;
  const int y0 = (tile / 6) * 6;
  const int grp = tid >> 8;      // 0 = even-t group, 1 = odd-t group
  const int gt  = tid & 255;     // thread id within group
  const int lane = tid & 63;
  const int ocg = (tid >> 6) & 3;
  const int px = lane & 15;
  const int kq = lane >> 4;

  // per-wave weights: 27 taps, gate-interleaved 16-slot frags
  half8 wreg[27];
  {
    const _Float16* wp = wr + (size_t)ocg * 27 * 512 + lane * 8;
#pragma unroll
    for (int tap = 0; tap < 27; ++tap)
      wreg[tap] = *(const half8*)(wp + tap * 512);
  }

  const int c0 = ocg * 8 + 2 * kq;
  f32x4 bias4;
  bias4[0] = bias[c0];
  bias4[1] = bias[32 + c0];
  bias4[2] = bias[c0 + 1];
  bias4[3] = bias[32 + c0 + 1];

  // staging roles within group (256 thr, R10 mapping)
  const int s_xi = gt & 15;
  const int s_q  = gt >> 4;
  const int e_cin = gt & 31;
  const int e_yy  = gt >> 5;
  const int e_gy  = y0 - 1 + e_yy;
  const bool e_ok = ((unsigned)e_gy < (unsigned)H_);
  const bool has_l = (x0 > 0), has_r = (x0 + 16 < W_);

  const float* inb = in + (size_t)(b * CIN_) * TSP;

  auto stage_g = [&](int ts) {   // prologue, group-cooperative
    _Float16* dst = in_s + SLOT(ts) * SLICE_HF;
    const int tso = ts * SP_;
#pragma unroll
    for (int k = 0; k < 16; ++k) {
      int rj = k * 16 + s_q;
      int cin = rj & 31;
      int yy = rj >> 5;
      int gy = y0 - 1 + yy;
      float v = 0.f;
      if ((unsigned)gy < (unsigned)H_)
        v = inb[(size_t)cin * TSP + tso + gy * W_ + x0 + s_xi];
      dst[(yy * SCOLS + s_xi + 1) * PITCH + cin] = (_Float16)v;
    }
    float v0 = 0.f, v1 = 0.f;
    if (e_ok) {
      const float* rb = inb + (size_t)e_cin * TSP + tso + e_gy * W_;
      if (has_l) v0 = rb[x0 - 1];
      if (has_r) v1 = rb[x0 + 16];
    }
    dst[(e_yy * SCOLS + 0) * PITCH + e_cin] = (_Float16)v0;
    dst[(e_yy * SCOLS + 17) * PITCH + e_cin] = (_Float16)v1;
  };

  // prologue: SLOT(5)=slice -1 zeros; hx zeros; slices 0,1,2 staged
  {
    uint32_t* dz = (uint32_t*)(in_s + 5 * SLICE_HF);
    for (int e = tid; e < SLICE_HF / 2; e += 512) dz[e] = 0u;
    for (int e = tid; e < 16 * 96; e += 512) hx_s[e] = 0u;
  }
  if (grp == 0) stage_g(0); else stage_g(1);
  if (grp == 0) stage_g(2);
  __syncthreads();

  const int pr = ocg * 4 + kq;             // packed pair plane 0..15
  const int hxb = pr * 96 + px;            // + r*16
  size_t obase = ((size_t)(b * 32 + pr) * T_ + grp) * SP_ + y0 * W_ + x0 + px;

  int cs[3];
#pragma unroll
  for (int kw = 0; kw < 3; ++kw) cs[kw] = (px + kw) * PITCH + kq * 8;

  for (int p = 0; p < 16; ++p) {
    const int t0 = 2 * p;
    const int tm = t0 + grp;               // this group's conv time
    const int ts = t0 + 3 + grp;           // this group's stage slice
    const bool do_conv = (tm < T_);        // false only for grp1 @ p=15
    const bool do_stage = (ts < T_);
    const bool do_zero  = (ts == T_);      // grp0 @ p=14 zeroes slice 31

    // ---- issue stage loads (held in regs; hidden under conv) ----
    float sv[16], ev0 = 0.f, ev1 = 0.f;
    if (do_stage) {
      const int tso = ts * SP_;
#pragma unroll
      for (int k = 0; k < 16; ++k) {
        int rj = k * 16 + s_q;
        int cin = rj & 31;
        int yy = rj >> 5;
        int gy = y0 - 1 + yy;
        sv[k] = 0.f;
        if ((unsigned)gy < (unsigned)H_)
          sv[k] = inb[(size_t)cin * TSP + tso + gy * W_ + x0 + s_xi];
      }
      if (e_ok) {
        const float* rb = inb + (size_t)e_cin * TSP + tso + e_gy * W_;
        if (has_l) ev0 = rb[x0 - 1];
        if (has_r) ev1 = rb[x0 + 16];
      }
    }

    // ---- conv for tm (R10 body): reads SLOT(tm-1 .. tm+1) ----
    f32x4 acc[6];
#pragma unroll
    for (int r = 0; r < 6; ++r) acc[r] = bias4;
    if (do_conv) {
#pragma unroll
      for (int kd = 0; kd < 3; ++kd) {
        const _Float16* sb2 = in_s + SLOT(tm - 1 + kd) * SLICE_HF;
#pragma unroll
        for (int kw = 0; kw < 3; ++kw) {
          half8 brow[8];
#pragma unroll
          for (int rr = 0; rr < 8; ++rr)
            brow[rr] = *(const half8*)(sb2 + rr * RST + cs[kw]);
#pragma unroll
          for (int kh = 0; kh < 3; ++kh) {
            const int tap = kd * 9 + kh * 3 + kw;
#pragma unroll
            for (int r = 0; r < 6; ++r)
              acc[r] = __builtin_amdgcn_mfma_f32_16x16x32_f16(
                  wreg[tap], brow[r + kh], acc[r], 0, 0, 0);
          }
        }
      }
    }

    // ---- write staged slice to its ring slot (outside read windows) ----
    if (do_stage) {
      _Float16* dst = in_s + SLOT(ts) * SLICE_HF;
#pragma unroll
      for (int k = 0; k < 16; ++k) {
        int rj = k * 16 + s_q;
        int cin = rj & 31;
        int yy = rj >> 5;
        dst[(yy * SCOLS + s_xi + 1) * PITCH + cin] = (_Float16)sv[k];
      }
      dst[(e_yy * SCOLS + 0) * PITCH + e_cin] = (_Float16)ev0;
      dst[(e_yy * SCOLS + 17) * PITCH + e_cin] = (_Float16)ev1;
    } else if (do_zero) {
      uint32_t* dz = (uint32_t*)(in_s + SLOT(T_) * SLICE_HF);
      for (int e = gt; e < SLICE_HF / 2; e += 256) dz[e] = 0u;
    }

    // ---- gating: A gates t0 (hx = h(t0-1), protected by last bar-end) ----
    unsigned int pk[6];
    bool stv = false;
    if (grp == 0) {
#pragma unroll
      for (int r = 0; r < 6; ++r) {
        unsigned int old = hx_s[hxb + r * 16];
        float h0 = (float)__builtin_bit_cast(_Float16, (unsigned short)(old & 0xffff));
        float h1 = (float)__builtin_bit_cast(_Float16, (unsigned short)(old >> 16));
        float z0 = 1.f - 2.f / (1.f + __expf(2.f * acc[r][0]));
        float f0 = 1.f / (1.f + __expf(-acc[r][1]));
        h0 = f0 * (h0 - z0) + z0;
        float z1 = 1.f - 2.f / (1.f + __expf(2.f * acc[r][2]));
        float f1 = 1.f / (1.f + __expf(-acc[r][3]));
        h1 = f1 * (h1 - z1) + z1;
        pk[r] = packhh(h0, h1);
        hx_s[hxb + r * 16] = pk[r];
      }
      stv = true;
    }
    __syncthreads();   // bar-mid: hx(t0) visible to B; slot writes visible

    if (grp == 1 && do_conv) {   // B gates t1 = t0+1
#pragma unroll
      for (int r = 0; r < 6; ++r) {
        unsigned int old = hx_s[hxb + r * 16];
        float h0 = (float)__builtin_bit_cast(_Float16, (unsigned short)(old & 0xffff));
        float h1 = (float)__builtin_bit_cast(_Float16, (unsigned short)(old >> 16));
        float z0 = 1.f - 2.f / (1.f + __expf(2.f * acc[r][0]));
        float f0 = 1.f / (1.f + __expf(-acc[r][1]));
        h0 = f0 * (h0 - z0) + z0;
        float z1 = 1.f - 2.f / (1.f + __expf(2.f * acc[r][2]));
        float f1 = 1.f / (1.f + __expf(-acc[r][3]));
        h1 = f1 * (h1 - z1) + z1;
        pk[r] = packhh(h0, h1);
        hx_s[hxb + r * 16] = pk[r];
      }
      stv = true;
    }
    __syncthreads();   // bar-end: hx(t1) for next A; ring safety

    // ---- stores after barrier (drain overlaps next phase) ----
    if (stv) {
#pragma unroll
      for (int r = 0; r < 6; ++r) gout[obase + r * W_] = pk[r];
    }
    obase += 2 * SP_;
  }
}

// ---------------------------------------------------------------------------
// Kernel 2: per-pixel channel attention via 32x32x16 MFMA. (proven R10)
// Reads packed f16x2 h from u32-planes b*32+pr at own (y,x) tile; writes
// final f32 to planes b*32+c at the same tile -> no cross-block aliasing.
// ---------------------------------------------------------------------------
#define APIT 40
#define PSTR 1288

__global__ __launch_bounds__(512) void attn_mfma(
    unsigned int* __restrict__ g, const float* __restrict__ gamma) {
  __shared__ _Float16 qh_s[16 * PSTR];
  __shared__ _Float16 qt_s[16 * PSTR];
  __shared__ _Float16 at_s[8 * 32 * APIT];

  const int tid = threadIdx.x;
  const int x0 = blockIdx.x * 16;
  const int y = blockIdx.y;
  const int b = blockIdx.z;
  const int lane = tid & 63;
  const int wv = tid >> 6;
  const float gm = gamma[0];

  for (int e = tid; e < 16 * 16 * 31; e += 512) {
    int xi = e & 15;
    int q = e >> 4;
    int t = q % 31;
    int pr = q / 31;
    unsigned int gw = g[((size_t)(b * 32 + pr) * T_ + t) * SP_ + y * W_ + x0 + xi];
    _Float16 h0 = __builtin_bit_cast(_Float16, (unsigned short)(gw & 0xffff));
    _Float16 h1 = __builtin_bit_cast(_Float16, (unsigned short)(gw >> 16));
    int c0 = 2 * pr;
    qh_s[xi * PSTR + c0 * APIT + t] = h0;
    qh_s[xi * PSTR + (c0 + 1) * APIT + t] = h1;
    qt_s[xi * PSTR + t * APIT + c0] = h0;
    qt_s[xi * PSTR + t * APIT + c0 + 1] = h1;
  }
  qh_s[(tid & 15) * PSTR + (tid >> 4) * APIT + 31] = (_Float16)0.f;
  __syncthreads();

  const int cd = lane & 31;
  const int hi = lane >> 5;

#pragma unroll
  for (int pp = 0; pp < 2; ++pp) {
    const int px = wv * 2 + pp;
    const _Float16* qs = qh_s + px * PSTR;
    const _Float16* qt = qt_s + px * PSTR;
    _Float16* as = at_s + wv * (32 * APIT);

    half8 q0 = *(const half8*)(qs + cd * APIT + hi * 8);
    half8 q1 = *(const half8*)(qs + cd * APIT + hi * 8 + 16);
    f32x16 S = {};
    S = __builtin_amdgcn_mfma_f32_32x32x16_f16(q0, q0, S, 0, 0, 0);
    S = __builtin_amdgcn_mfma_f32_32x32x16_f16(q1, q1, S, 0, 0, 0);

    float mx = S[0];
#pragma unroll
    for (int r = 1; r < 16; ++r) mx = fmaxf(mx, S[r]);
    mx = fmaxf(mx, __shfl_xor(mx, 32));
    float sm = 0.f;
    float ev[16];
#pragma unroll
    for (int r = 0; r < 16; ++r) { ev[r] = __expf(S[r] - mx); sm += ev[r]; }
    sm += __shfl_xor(sm, 32);
    const float sc = 0.17677669529663688f / sm;

#pragma unroll
    for (int r = 0; r < 16; ++r) {
      int c = (r & 3) + 8 * (r >> 2) + 4 * hi;
      as[c * APIT + cd] = (_Float16)(ev[r] * sc);
    }

    half8 a0 = *(const half8*)(as + cd * APIT + hi * 8);
    half8 a1 = *(const half8*)(as + cd * APIT + hi * 8 + 16);
    half8 b0 = *(const half8*)(qt + cd * APIT + hi * 8);
    half8 b1 = *(const half8*)(qt + cd * APIT + hi * 8 + 16);
    f32x16 P = {};
    P = __builtin_amdgcn_mfma_f32_32x32x16_f16(a0, b0, P, 0, 0, 0);
    P = __builtin_amdgcn_mfma_f32_32x32x16_f16(a1, b1, P, 0, 0, 0);

#pragma unroll
    for (int r = 0; r < 16; ++r) {
      int c = (r & 3) + 8 * (r >> 2) + 4 * hi;
      qt_s[px * PSTR + cd * APIT + c] = (_Float16)P[r];
    }
  }
  __syncthreads();

  float* gf = (float*)g;
  for (int e = tid; e < 4 * 992; e += 512) {
    int xi4 = e & 3;
    int q = e >> 2;
    int t = q % 31;
    int c = q / 31;
    float4 rv;
#pragma unroll
    for (int j = 0; j < 4; ++j) {
      int xi = xi4 * 4 + j;
      float ah = (float)qt_s[xi * PSTR + t * APIT + c];
      float hv = (float)qh_s[xi * PSTR + c * APIT + t];
      (&rv.x)[j] = gm * ah + hv;
    }
    *(float4*)&gf[((size_t)(b * HID_ + c) * T_ + t) * SP_ + y * W_ + x0 +
                  xi4 * 4] = rv;
  }
}

// ---------------------------------------------------------------------------
extern "C" void kernel_launch(void* const* d_in, const int* in_sizes, int n_in,
                              void* d_out, int out_size, void* d_ws,
                              size_t ws_size, hipStream_t stream) {
  const float* in    = (const float*)d_in[0];  // [4,32,31,96,96]
  const float* w     = (const float*)d_in[1];  // [64,32,3,3,3]
  const float* bias  = (const float*)d_in[2];  // [64]
  const float* gamma = (const float*)d_in[3];  // [1]
  _Float16* wr = (_Float16*)d_ws;              // 110 KB fp16 fragments

  prep_w_kernel<<<216, 256, 0, stream>>>(w, wr);
  conv_rec_mfma<<<dim3(96, 4), 512, 0, stream>>>(
      in, wr, bias, (unsigned int*)d_out);
  attn_mfma<<<dim3(6, 96, 4), 512, 0, stream>>>(
      (unsigned int*)d_out, gamma);
}

// Round 15
// 297.184 us; speedup vs baseline: 2.0250x; 1.3628x over previous
//
#include <hip/hip_runtime.h>
#include <math.h>

#define B_ 4
#define CIN_ 32
#define HID_ 32
#define T_ 31
#define H_ 96
#define W_ 96
#define SP_ (H_*W_)
#define TSP (T_ * SP_)

typedef _Float16 half8 __attribute__((ext_vector_type(8)));
typedef float f32x4 __attribute__((ext_vector_type(4)));
typedef float f32x16 __attribute__((ext_vector_type(16)));

static __device__ inline unsigned int packhh(float a, float b) {
  unsigned short ua = __builtin_bit_cast(unsigned short, (_Float16)a);
  unsigned short ub = __builtin_bit_cast(unsigned short, (_Float16)b);
  return (unsigned int)ua | ((unsigned int)ub << 16);
}

// ---------------------------------------------------------------------------
// Kernel 0: weights fp32 -> fp16 gate-interleaved MFMA A-fragments.
// wr[((ocg*27 + tap)*64 + lane)*8 + i]
//   m = lane&15: gate = m&1, ch = ocg*8 + (m>>1); oc = gate*32 + ch
//   cin = (lane>>4)*8 + i
// ---------------------------------------------------------------------------
__global__ __launch_bounds__(256) void prep_w_kernel(
    const float* __restrict__ w, _Float16* __restrict__ wr) {
  int idx = blockIdx.x * 256 + threadIdx.x;
  if (idx >= 55296) return;
  int i = idx & 7;
  int lane = (idx >> 3) & 63;
  int rest = idx >> 9;             // ocg*27 + tap
  int tap = rest % 27;
  int ocg = rest / 27;
  int m = lane & 15;
  int cin = (lane >> 4) * 8 + i;
  int oc = (m & 1) * 32 + ocg * 8 + (m >> 1);
  wr[idx] = (_Float16)(w[(oc * CIN_ + cin) * 27 + tap]);
}

// ---------------------------------------------------------------------------
// Kernel 1: fused Conv3d (fp16 MFMA) + gating + SERIAL recurrence.
// R10/R11 proven frame (4 waves x 16 oc-slots, tile 16x6, grid 96x4,
// in-VGPR weights, packed fp16x2 out, stores-after-barrier, NO swizzle)
// + 2-DEEP STAGE PIPELINE (T14 async-split): phase t issues loads for
// slice t+3 (into svA/svB alternating, NAMED arrays via 2-unrolled loop —
// no dynamic reg indexing); ds_writes slice t+2 loaded LAST phase, so the
// vmcnt wait has a full phase (~18k cyc) of slack instead of ~0.
// Ring: 6 slots x [8r x 18c][pitch 40] = 69 KB -> 2 blocks/CU.
// Slot safety (phase t): reads SLOT(t-1..t+1); writes SLOT(t+2)=SLOT(t-4):
// disjoint mod 6; slice t-4 last read phase t-3, barriers between.
// launch_bounds(256,1): compiler free to ~220 VGPR (R12 proved no-spill);
// VGPR<=256 keeps 2 waves/SIMD; occupancy LDS-capped at 2 blocks/CU.
// ---------------------------------------------------------------------------
#define PITCH 40
#define SROWS 8
#define SCOLS 18
#define RST (SCOLS * PITCH)
#define SLICE_HF (SROWS * RST)             // 5760 f16 = 11520 B
#define SLOT(s) ((((s) % 6) + 6) % 6)

#define ISSUE_LOADS(ts, sv, ev0, ev1)                                   \
  {                                                                     \
    const int tso = (ts) * SP_;                                         \
    _Pragma("unroll")                                                   \
    for (int k = 0; k < 16; ++k) {                                      \
      int rj = k * 16 + s_q;                                            \
      int cin = rj & 31;                                                \
      int yy = rj >> 5;                                                 \
      int gy = y0 - 1 + yy;                                             \
      sv[k] = 0.f;                                                      \
      if ((unsigned)gy < (unsigned)H_)                                  \
        sv[k] = inb[(size_t)cin * TSP + tso + gy * W_ + x0 + s_xi];     \
    }                                                                   \
    ev0 = 0.f; ev1 = 0.f;                                               \
    if (e_ok) {                                                         \
      const float* rb = inb + (size_t)e_cin * TSP + tso + e_gy * W_;    \
      if (has_l) ev0 = rb[x0 - 1];                                      \
      if (has_r) ev1 = rb[x0 + 16];                                     \
    }                                                                   \
  }

#define WRITE_SLICE(ts, sv, ev0, ev1)                                   \
  {                                                                     \
    _Float16* dst = in_s + SLOT(ts) * SLICE_HF;                         \
    _Pragma("unroll")                                                   \
    for (int k = 0; k < 16; ++k) {                                      \
      int rj = k * 16 + s_q;                                            \
      int cin = rj & 31;                                                \
      int yy = rj >> 5;                                                 \
      dst[(yy * SCOLS + s_xi + 1) * PITCH + cin] = (_Float16)sv[k];     \
    }                                                                   \
    dst[(e_yy * SCOLS + 0) * PITCH + e_cin] = (_Float16)ev0;            \
    dst[(e_yy * SCOLS + 17) * PITCH + e_cin] = (_Float16)ev1;           \
  }

// One time-phase: issue loads slice tcur+3 into (svL), compute conv(tcur),
// ds_write slice tcur+2 from (svW) [loaded last phase], gate, barrier, store.
#define PHASE(tcur, svW, evW0, evW1, svL, evL0, evL1)                   \
  {                                                                     \
    const int tsL = (tcur) + 3;                                         \
    if (tsL < T_) ISSUE_LOADS(tsL, svL, evL0, evL1);                    \
    f32x4 acc[6];                                                       \
    _Pragma("unroll") for (int r = 0; r < 6; ++r) acc[r] = bias4;       \
    _Pragma("unroll")                                                   \
    for (int kd = 0; kd < 3; ++kd) {                                    \
      const _Float16* sb2 = in_s + SLOT((tcur) - 1 + kd) * SLICE_HF;    \
      _Pragma("unroll")                                                 \
      for (int kw = 0; kw < 3; ++kw) {                                  \
        half8 brow[8];                                                  \
        _Pragma("unroll")                                               \
        for (int rr = 0; rr < 8; ++rr)                                  \
          brow[rr] = *(const half8*)(sb2 + rr * RST + cs[kw]);          \
        _Pragma("unroll")                                               \
        for (int kh = 0; kh < 3; ++kh) {                                \
          const int tap = kd * 9 + kh * 3 + kw;                         \
          _Pragma("unroll")                                             \
          for (int r = 0; r < 6; ++r)                                   \
            acc[r] = __builtin_amdgcn_mfma_f32_16x16x32_f16(            \
                wreg[tap], brow[r + kh], acc[r], 0, 0, 0);              \
        }                                                               \
      }                                                                 \
    }                                                                   \
    const int tsW = (tcur) + 2;                                         \
    if (tsW < T_) {                                                     \
      WRITE_SLICE(tsW, svW, evW0, evW1);                                \
    } else if (tsW == T_) {                                             \
      uint32_t* dz = (uint32_t*)(in_s + SLOT(T_) * SLICE_HF);           \
      for (int e = tid; e < SLICE_HF / 2; e += 256) dz[e] = 0u;         \
    }                                                                   \
    unsigned int pk[6];                                                 \
    _Pragma("unroll")                                                   \
    for (int r = 0; r < 6; ++r) {                                       \
      float z0 = 1.f - 2.f / (1.f + __expf(2.f * acc[r][0]));           \
      float f0 = 1.f / (1.f + __expf(-acc[r][1]));                      \
      h[r][0] = f0 * (h[r][0] - z0) + z0;                               \
      float z1 = 1.f - 2.f / (1.f + __expf(2.f * acc[r][2]));           \
      float f1 = 1.f / (1.f + __expf(-acc[r][3]));                      \
      h[r][1] = f1 * (h[r][1] - z1) + z1;                               \
      pk[r] = packhh(h[r][0], h[r][1]);                                 \
    }                                                                   \
    __syncthreads();                                                    \
    _Pragma("unroll")                                                   \
    for (int r = 0; r < 6; ++r) gout[obase + r * W_] = pk[r];           \
    obase += SP_;                                                       \
  }

__global__ __launch_bounds__(256, 1) void conv_rec_mfma(
    const float* __restrict__ in, const _Float16* __restrict__ wr,
    const float* __restrict__ bias, unsigned int* __restrict__ gout) {
  __shared__ _Float16 in_s[6 * SLICE_HF];   // 69120 B

  const int tid = threadIdx.x;
  const int tile = blockIdx.x;   // 0..95
  const int b = blockIdx.y;      // 0..3
  const int x0 = (tile % 6) * 16;
  const int y0 = (tile / 6) * 6;
  const int lane = tid & 63;
  const int ocg = tid >> 6;      // 0..3
  const int px = lane & 15;
  const int kq = lane >> 4;      // 0..3

  // per-wave weights: 27 taps, gate-interleaved 16-slot frags (108 VGPR)
  half8 wreg[27];
  {
    const _Float16* wp = wr + (size_t)ocg * 27 * 512 + lane * 8;
#pragma unroll
    for (int tap = 0; tap < 27; ++tap)
      wreg[tap] = *(const half8*)(wp + tap * 512);
  }

  const int c0 = ocg * 8 + 2 * kq;
  f32x4 bias4;
  bias4[0] = bias[c0];
  bias4[1] = bias[32 + c0];
  bias4[2] = bias[c0 + 1];
  bias4[3] = bias[32 + c0 + 1];

  // staging roles: interior 16 jobs x 16 px; edges 8 rows x 32 cin
  const int s_xi = tid & 15;
  const int s_q  = tid >> 4;
  const int e_cin = tid & 31;
  const int e_yy  = tid >> 5;
  const int e_gy  = y0 - 1 + e_yy;
  const bool e_ok = ((unsigned)e_gy < (unsigned)H_);
  const bool has_l = (x0 > 0), has_r = (x0 + 16 < W_);

  const float* inb = in + (size_t)(b * CIN_) * TSP;

  // brow column offsets (no swizzle — R11's swizzle measured harmful)
  int cs[3];
#pragma unroll
  for (int kw = 0; kw < 3; ++kw) cs[kw] = (px + kw) * PITCH + kq * 8;

  // prologue: SLOT(5) = slice -1 zeros; slices 0,1 staged directly;
  // slice 2 pre-issued into svB (consumed by phase 0's WRITE).
  {
    uint32_t* dz = (uint32_t*)(in_s + 5 * SLICE_HF);
    for (int e = tid; e < SLICE_HF / 2; e += 256) dz[e] = 0u;
  }
  float svA[16], evA0 = 0.f, evA1 = 0.f;
  float svB[16], evB0 = 0.f, evB1 = 0.f;
  ISSUE_LOADS(0, svA, evA0, evA1);
  WRITE_SLICE(0, svA, evA0, evA1);
  ISSUE_LOADS(1, svA, evA0, evA1);
  WRITE_SLICE(1, svA, evA0, evA1);
  ISSUE_LOADS(2, svB, evB0, evB1);
  __syncthreads();

  float h[6][2];
#pragma unroll
  for (int r = 0; r < 6; ++r) { h[r][0] = 0.f; h[r][1] = 0.f; }

  const int pr = ocg * 4 + kq;   // packed pair plane 0..15
  size_t obase = ((size_t)(b * 32 + pr) * T_) * SP_ + y0 * W_ + x0 + px;

  // phases 0..29 as even/odd pairs (named sv buffers alternate), then t=30
  for (int t0 = 0; t0 < T_ - 1; t0 += 2) {
    PHASE(t0,     svB, evB0, evB1, svA, evA0, evA1);
    PHASE(t0 + 1, svA, evA0, evA1, svB, evB0, evB1);
  }
  PHASE(T_ - 1, svB, evB0, evB1, svA, evA0, evA1);  // t=30: no load, no write
}

// ---------------------------------------------------------------------------
// Kernel 2: per-pixel channel attention via 32x32x16 MFMA. (proven R10)
// Reads packed f16x2 h from u32-planes b*32+pr at own (y,x) tile; writes
// final f32 to planes b*32+c at the same tile -> no cross-block aliasing.
// ---------------------------------------------------------------------------
#define APIT 40
#define PSTR 1288

__global__ __launch_bounds__(512) void attn_mfma(
    unsigned int* __restrict__ g, const float* __restrict__ gamma) {
  __shared__ _Float16 qh_s[16 * PSTR];
  __shared__ _Float16 qt_s[16 * PSTR];
  __shared__ _Float16 at_s[8 * 32 * APIT];

  const int tid = threadIdx.x;
  const int x0 = blockIdx.x * 16;
  const int y = blockIdx.y;
  const int b = blockIdx.z;
  const int lane = tid & 63;
  const int wv = tid >> 6;
  const float gm = gamma[0];

  for (int e = tid; e < 16 * 16 * 31; e += 512) {
    int xi = e & 15;
    int q = e >> 4;
    int t = q % 31;
    int pr = q / 31;
    unsigned int gw = g[((size_t)(b * 32 + pr) * T_ + t) * SP_ + y * W_ + x0 + xi];
    _Float16 h0 = __builtin_bit_cast(_Float16, (unsigned short)(gw & 0xffff));
    _Float16 h1 = __builtin_bit_cast(_Float16, (unsigned short)(gw >> 16));
    int c0 = 2 * pr;
    qh_s[xi * PSTR + c0 * APIT + t] = h0;
    qh_s[xi * PSTR + (c0 + 1) * APIT + t] = h1;
    qt_s[xi * PSTR + t * APIT + c0] = h0;
    qt_s[xi * PSTR + t * APIT + c0 + 1] = h1;
  }
  qh_s[(tid & 15) * PSTR + (tid >> 4) * APIT + 31] = (_Float16)0.f;
  __syncthreads();

  const int cd = lane & 31;
  const int hi = lane >> 5;

#pragma unroll
  for (int pp = 0; pp < 2; ++pp) {
    const int px = wv * 2 + pp;
    const _Float16* qs = qh_s + px * PSTR;
    const _Float16* qt = qt_s + px * PSTR;
    _Float16* as = at_s + wv * (32 * APIT);

    half8 q0 = *(const half8*)(qs + cd * APIT + hi * 8);
    half8 q1 = *(const half8*)(qs + cd * APIT + hi * 8 + 16);
    f32x16 S = {};
    S = __builtin_amdgcn_mfma_f32_32x32x16_f16(q0, q0, S, 0, 0, 0);
    S = __builtin_amdgcn_mfma_f32_32x32x16_f16(q1, q1, S, 0, 0, 0);

    float mx = S[0];
#pragma unroll
    for (int r = 1; r < 16; ++r) mx = fmaxf(mx, S[r]);
    mx = fmaxf(mx, __shfl_xor(mx, 32));
    float sm = 0.f;
    float ev[16];
#pragma unroll
    for (int r = 0; r < 16; ++r) { ev[r] = __expf(S[r] - mx); sm += ev[r]; }
    sm += __shfl_xor(sm, 32);
    const float sc = 0.17677669529663688f / sm;

#pragma unroll
    for (int r = 0; r < 16; ++r) {
      int c = (r & 3) + 8 * (r >> 2) + 4 * hi;
      as[c * APIT + cd] = (_Float16)(ev[r] * sc);
    }

    half8 a0 = *(const half8*)(as + cd * APIT + hi * 8);
    half8 a1 = *(const half8*)(as + cd * APIT + hi * 8 + 16);
    half8 b0 = *(const half8*)(qt + cd * APIT + hi * 8);
    half8 b1 = *(const half8*)(qt + cd * APIT + hi * 8 + 16);
    f32x16 P = {};
    P = __builtin_amdgcn_mfma_f32_32x32x16_f16(a0, b0, P, 0, 0, 0);
    P = __builtin_amdgcn_mfma_f32_32x32x16_f16(a1, b1, P, 0, 0, 0);

#pragma unroll
    for (int r = 0; r < 16; ++r) {
      int c = (r & 3) + 8 * (r >> 2) + 4 * hi;
      qt_s[px * PSTR + cd * APIT + c] = (_Float16)P[r];
    }
  }
  __syncthreads();

  float* gf = (float*)g;
  for (int e = tid; e < 4 * 992; e += 512) {
    int xi4 = e & 3;
    int q = e >> 2;
    int t = q % 31;
    int c = q / 31;
    float4 rv;
#pragma unroll
    for (int j = 0; j < 4; ++j) {
      int xi = xi4 * 4 + j;
      float ah = (float)qt_s[xi * PSTR + t * APIT + c];
      float hv = (float)qh_s[xi * PSTR + c * APIT + t];
      (&rv.x)[j] = gm * ah + hv;
    }
    *(float4*)&gf[((size_t)(b * HID_ + c) * T_ + t) * SP_ + y * W_ + x0 +
                  xi4 * 4] = rv;
  }
}

// ---------------------------------------------------------------------------
extern "C" void kernel_launch(void* const* d_in, const int* in_sizes, int n_in,
                              void* d_out, int out_size, void* d_ws,
                              size_t ws_size, hipStream_t stream) {
  const float* in    = (const float*)d_in[0];  // [4,32,31,96,96]
  const float* w     = (const float*)d_in[1];  // [64,32,3,3,3]
  const float* bias  = (const float*)d_in[2];  // [64]
  const float* gamma = (const float*)d_in[3];  // [1]
  _Float16* wr = (_Float16*)d_ws;              // 110 KB fp16 fragments

  prep_w_kernel<<<216, 256, 0, stream>>>(w, wr);
  conv_rec_mfma<<<dim3(96, 4), 256, 0, stream>>>(
      in, wr, bias, (unsigned int*)d_out);
  attn_mfma<<<dim3(6, 96, 4), 512, 0, stream>>>(
      (unsigned int*)d_out, gamma);
}